// Round 11
// baseline (23.624 us; speedup 1.0000x reference)
//
#include <hip/hip_runtime.h>

#define NROWS 8192
#define INCH 10
#define NQKV 33
#define OUTCH 11
#define QBLK 32           // q-rows per block; all 8 waves share them
#define KWAVE 1024        // k-rows per wave (8 waves cover all 8192)
#define KTILE 64          // k-rows per staged tile (double-buffered per wave)

typedef short short8 __attribute__((ext_vector_type(8)));
typedef float f32x16 __attribute__((ext_vector_type(16)));
typedef unsigned int uvec4 __attribute__((ext_vector_type(4)));

// ws byte layout:
//   QB_OFF: Q bf16 [NROWS][16ch] rows of 32B (scale*log2e folded into q)
//   KB_OFF: K bf16 planes [2][NROWS][16B]: plane c holds ch 8c..8c+7
//   VT_OFF: V^T bf16 interleaved: 16B unit u=(k>>3)*16+d holds V[(k&~7)+slot][d],
//           d=0..10 v, d=11 ones (softmax denom), d=12..15 zero
#define QB_OFF   0
#define KB_OFF   (NROWS * 32)
#define VT_OFF   (2 * NROWS * 32)

#define AS1 __attribute__((address_space(1)))
#define AS3 __attribute__((address_space(3)))

// v_permlane32_swap_b32 a, b:
//   a' = {a.lo32lanes, b.lo32lanes}, b' = {a.hi32lanes, b.hi32lanes}
#define SWAP32(a, b) asm("v_permlane32_swap_b32 %0, %1" : "+v"(a), "+v"(b))

__device__ inline unsigned short f2bf(float f) {
  unsigned u = __float_as_uint(f);
  unsigned r = (u + 0x7FFFu + ((u >> 16) & 1u)) >> 16;  // RNE
  return (unsigned short)r;
}

// ---------------------------------------------------------------------------
// Kernel A (r4-proven, unchanged): LayerNorm + Linear(10->33);
// emit bf16 Q rows, K planes, V^T.
// ---------------------------------------------------------------------------
__global__ __launch_bounds__(64) void qkv_ln_kernel(
    const float* __restrict__ x, const float* __restrict__ gamma,
    const float* __restrict__ beta, const float* __restrict__ W,
    char* __restrict__ ws) {
  __shared__ float sW[NQKV * INCH];
  __shared__ float sg[INCH];
  __shared__ float sb[INCH];
  int tid = threadIdx.x;
  for (int i = tid; i < NQKV * INCH; i += 64) sW[i] = W[i];
  if (tid < INCH) { sg[tid] = gamma[tid]; sb[tid] = beta[tid]; }
  __syncthreads();

  int row = blockIdx.x * 64 + tid;
  const float2* x2 = (const float2*)x;  // rows are 40B = 5 float2, 8B aligned
  float xv[INCH];
#pragma unroll
  for (int j = 0; j < 5; ++j) {
    float2 t = x2[row * 5 + j];
    xv[2 * j] = t.x;
    xv[2 * j + 1] = t.y;
  }

  float mu = 0.f;
#pragma unroll
  for (int i = 0; i < INCH; ++i) mu += xv[i];
  mu *= (1.0f / INCH);
  float var = 0.f;
#pragma unroll
  for (int i = 0; i < INCH; ++i) { float d = xv[i] - mu; var += d * d; }
  var *= (1.0f / INCH);
  float rstd = rsqrtf(var + 1e-5f);
  float h[INCH];
#pragma unroll
  for (int i = 0; i < INCH; ++i) h[i] = (xv[i] - mu) * rstd * sg[i] + sb[i];

  float acc[NQKV];
#pragma unroll
  for (int oc = 0; oc < NQKV; ++oc) {
    float s = 0.f;
#pragma unroll
    for (int i = 0; i < INCH; ++i) s += h[i] * sW[oc * INCH + i];
    acc[oc] = s;
  }

  // exp(s*scale) = exp2(s*scale*log2e): fold into q.
  const float QSC = 0.31622776601683794f * 1.4426950408889634f;

  unsigned short e[16];
  unsigned qw[8];
  // ---- Q row ----
#pragma unroll
  for (int i = 0; i < 16; ++i) e[i] = (i < OUTCH) ? f2bf(acc[i] * QSC) : 0;
#pragma unroll
  for (int i = 0; i < 8; ++i)
    qw[i] = (unsigned)e[2 * i] | ((unsigned)e[2 * i + 1] << 16);
  uint4* Qb = (uint4*)(ws + QB_OFF);
  Qb[row * 2 + 0] = make_uint4(qw[0], qw[1], qw[2], qw[3]);
  Qb[row * 2 + 1] = make_uint4(qw[4], qw[5], qw[6], qw[7]);
  // ---- K planes ----
#pragma unroll
  for (int i = 0; i < 16; ++i) e[i] = (i < OUTCH) ? f2bf(acc[OUTCH + i]) : 0;
#pragma unroll
  for (int i = 0; i < 8; ++i)
    qw[i] = (unsigned)e[2 * i] | ((unsigned)e[2 * i + 1] << 16);
  uint4* Kb = (uint4*)(ws + KB_OFF);
  Kb[row] = make_uint4(qw[0], qw[1], qw[2], qw[3]);          // plane 0
  Kb[NROWS + row] = make_uint4(qw[4], qw[5], qw[6], qw[7]);  // plane 1
  // ---- V^T scatter (2B stores into interleaved units) ----
  unsigned short* VTu = (unsigned short*)(ws + VT_OFF);
  int u0 = (row >> 3) * 16;
  int slot = row & 7;
#pragma unroll
  for (int d = 0; d < 16; ++d) {
    unsigned short v;
    if (d < OUTCH)       v = f2bf(acc[2 * OUTCH + d]);
    else if (d == OUTCH) v = 0x3F80;  // ones column -> softmax denominator
    else                 v = 0;
    VTu[(u0 + d) * 8 + slot] = v;
  }
}

// ---------------------------------------------------------------------------
// Kernel B (r9 structure, KTILE 128->64 so LDS = 80 KB -> 2 blocks/CU =
// 4 waves/SIMD; the single change this round). 256 blocks x 512 thr (8
// waves). All waves share the block's 32 q-rows; wave w streams k-chunk
// [w*1024, w*1024+1024) through its PRIVATE double-buffered LDS region
// (no barriers in the main loop). Counted s_waitcnt vmcnt(4) keeps the
// next tile's 4 global_load_lds in flight across compute (T4 idiom).
// Inner tile = r4's proven pipeline: S^T = mfma(K,Q); p = exp2(S);
// v_perm bf16 pack; permlane32_swap -> PV A-frags; O += mfma(P,V) x2;
// V ones-column yields the denominator. No row-max (|s|<=~13, fp32-safe).
// Epilogue: one __syncthreads, sum 8 wave-partials from LDS, normalize.
// ---------------------------------------------------------------------------
__global__ __launch_bounds__(512) void attn_kernel(const char* __restrict__ ws,
                                                   float* __restrict__ out) {
  __shared__ uint4 sStage[8 * 512];         // 64 KB: per-wave [2][256] uint4
  __shared__ float sPart[8 * QBLK * 16];    // 16 KB: per-wave (o,l) tiles

  const int tid = threadIdx.x;
  const int lane = tid & 63;
  const int w = tid >> 6;       // wave id = k-chunk id
  const int h = lane >> 5;
  const int l31 = lane & 31;
  const int q0 = blockIdx.x * QBLK;
  const int kbase = w * KWAVE;

  const uint4* gK = (const uint4*)(ws + KB_OFF);  // [2][NROWS] 16B units
  const uint4* gV = (const uint4*)(ws + VT_OFF);  // [NROWS*2]  16B units

  uint4* myStage = sStage + w * 512;  // 8 KB private: two 4 KB buffers

  // stage tile (64 k-rows) into buffer b: [0,128)=K planes, [128,256)=V^T
#define STAGE(b, k0)                                                         \
  {                                                                          \
    uint4* buf = myStage + (b) * 256;                                        \
    _Pragma("unroll") for (int c = 0; c < 2; ++c) {                          \
      __builtin_amdgcn_global_load_lds(                                      \
          (const AS1 void*)(gK + c * NROWS + (k0) + lane),                   \
          (AS3 void*)(buf + c * 64), 16, 0, 0);                              \
    }                                                                        \
    _Pragma("unroll") for (int i = 0; i < 2; ++i) {                          \
      __builtin_amdgcn_global_load_lds(                                      \
          (const AS1 void*)(gV + (k0) * 2 + i * 64 + lane),                  \
          (AS3 void*)(buf + 128 + i * 64), 16, 0, 0);                        \
    }                                                                        \
  }

  STAGE(0, kbase)

  // Q fragment straight from global (L2-hot): Q[q0+(lane&31)][ch 8h..8h+7]
  short8 qf = *(const short8*)(ws + QB_OFF + (q0 + l31) * 32 + h * 16);

  f32x16 oacc, zf;
#pragma unroll
  for (int r = 0; r < 16; ++r) { oacc[r] = 0.f; zf[r] = 0.f; }

  for (int t = 0; t < KWAVE / KTILE; ++t) {  // 16 tiles of 64 rows
    if (t < KWAVE / KTILE - 1) {
      STAGE((t + 1) & 1, kbase + (t + 1) * KTILE)
      asm volatile("s_waitcnt vmcnt(4)" ::: "memory");
    } else {
      asm volatile("s_waitcnt vmcnt(0)" ::: "memory");
    }
    __builtin_amdgcn_sched_barrier(0);

    const char* buf = (const char*)(myStage + (t & 1) * 256);
    const char* vb = buf + 2048;
#pragma unroll
    for (int it = 0; it < KTILE / 32; ++it) {
      // K fragment: plane h (stride 1 KB), rows it*32 + l31 -> 16B/lane
      short8 kf = *(const short8*)(buf + h * 1024 + (it * 32 + l31) * 16);
      f32x16 s = __builtin_amdgcn_mfma_f32_32x32x16_bf16(kf, qf, zf, 0, 0, 0);

      float p[16];
#pragma unroll
      for (int r = 0; r < 16; ++r) p[r] = __builtin_amdgcn_exp2f(s[r]);

#define PK(a, b) __builtin_amdgcn_perm(__float_as_uint(b), __float_as_uint(a), 0x07060302u)
      unsigned P01 = PK(p[0], p[1]), P23 = PK(p[2], p[3]);
      unsigned P45 = PK(p[4], p[5]), P67 = PK(p[6], p[7]);
      unsigned P89 = PK(p[8], p[9]), Pab = PK(p[10], p[11]);
      unsigned Pcd = PK(p[12], p[13]), Pef = PK(p[14], p[15]);
#undef PK
      SWAP32(P01, P45);
      SWAP32(P23, P67);
      SWAP32(P89, Pcd);
      SWAP32(Pab, Pef);
      uvec4 c0 = {P01, P23, P45, P67};  // k 0..15: word j = P[q][k=8h+2j..]
      uvec4 c1 = {P89, Pab, Pcd, Pef};  // k 16..31
      short8 a0 = __builtin_bit_cast(short8, c0);
      short8 a1 = __builtin_bit_cast(short8, c1);

      // V fragments: lane holds V[k=16c'+8h+i][d=lane&15]
      short8 v0 = *(const short8*)(vb + (it * 4 + h) * 256 + (lane & 15) * 16);
      short8 v1 = *(const short8*)(vb + (it * 4 + 2 + h) * 256 + (lane & 15) * 16);

      oacc = __builtin_amdgcn_mfma_f32_32x32x16_bf16(a0, v0, oacc, 0, 0, 0);
      oacc = __builtin_amdgcn_mfma_f32_32x32x16_bf16(a1, v1, oacc, 0, 0, 0);
    }
  }
#undef STAGE

  // wave-partials -> LDS; d = lane&31 < 12, q unique per (r,h)
  if (l31 < 12) {
#pragma unroll
    for (int r = 0; r < 16; ++r) {
      int q = (r & 3) + 8 * (r >> 2) + 4 * h;
      sPart[(w * QBLK + q) * 16 + l31] = oacc[r];
    }
  }
  __syncthreads();

  // in-block combine + normalize: thread (q = tid>>4, c = tid&15)
  {
    int q = tid >> 4;
    int c = tid & 15;
    if (c < OUTCH) {
      float o = 0.f, l = 0.f;
#pragma unroll
      for (int wv = 0; wv < 8; ++wv) {
        o += sPart[(wv * QBLK + q) * 16 + c];
        l += sPart[(wv * QBLK + q) * 16 + 11];
      }
      out[(size_t)(q0 + q) * OUTCH + c] = o / l;
    }
  }
}

extern "C" void kernel_launch(void* const* d_in, const int* in_sizes, int n_in,
                              void* d_out, int out_size, void* d_ws, size_t ws_size,
                              hipStream_t stream) {
  const float* x = (const float*)d_in[0];
  const float* gamma = (const float*)d_in[1];
  const float* beta = (const float*)d_in[2];
  const float* W = (const float*)d_in[3];
  char* ws = (char*)d_ws;  // 768 KB of Q/K/V planes
  float* out = (float*)d_out;

  qkv_ln_kernel<<<NROWS / 64, 64, 0, stream>>>(x, gamma, beta, W, ws);
  attn_kernel<<<NROWS / QBLK, 512, 0, stream>>>(ws, out);
}

// Round 12
// 22.420 us; speedup vs baseline: 1.0537x; 1.0537x over previous
//
#include <hip/hip_runtime.h>

#define NROWS 8192
#define INCH 10
#define NQKV 33
#define OUTCH 11
#define QBLK 32           // q-rows per block; all 8 waves share them
#define KWAVE 1024        // k-rows per wave (8 waves cover all 8192)
#define KTILE 128         // k-rows per staged tile (double-buffered per wave)

typedef short short8 __attribute__((ext_vector_type(8)));
typedef float f32x16 __attribute__((ext_vector_type(16)));
typedef unsigned int uvec4 __attribute__((ext_vector_type(4)));

// ws byte layout:
//   QB_OFF: Q bf16 [NROWS][16ch] rows of 32B (scale*log2e folded into q)
//   KB_OFF: K bf16 planes [2][NROWS][16B]: plane c holds ch 8c..8c+7
//   VT_OFF: V^T bf16 interleaved: 16B unit u=(k>>3)*16+d holds V[(k&~7)+slot][d],
//           d=0..10 v, d=11 ones (softmax denom), d=12..15 zero
#define QB_OFF   0
#define KB_OFF   (NROWS * 32)
#define VT_OFF   (2 * NROWS * 32)

#define AS1 __attribute__((address_space(1)))
#define AS3 __attribute__((address_space(3)))

// v_permlane32_swap_b32 a, b:
//   a' = {a.lo32lanes, b.lo32lanes}, b' = {a.hi32lanes, b.hi32lanes}
#define SWAP32(a, b) asm("v_permlane32_swap_b32 %0, %1" : "+v"(a), "+v"(b))

__device__ inline unsigned short f2bf(float f) {
  unsigned u = __float_as_uint(f);
  unsigned r = (u + 0x7FFFu + ((u >> 16) & 1u)) >> 16;  // RNE
  return (unsigned short)r;
}

// ---------------------------------------------------------------------------
// Kernel A (r4-proven, unchanged): LayerNorm + Linear(10->33);
// emit bf16 Q rows, K planes, V^T.
// ---------------------------------------------------------------------------
__global__ __launch_bounds__(64) void qkv_ln_kernel(
    const float* __restrict__ x, const float* __restrict__ gamma,
    const float* __restrict__ beta, const float* __restrict__ W,
    char* __restrict__ ws) {
  __shared__ float sW[NQKV * INCH];
  __shared__ float sg[INCH];
  __shared__ float sb[INCH];
  int tid = threadIdx.x;
  for (int i = tid; i < NQKV * INCH; i += 64) sW[i] = W[i];
  if (tid < INCH) { sg[tid] = gamma[tid]; sb[tid] = beta[tid]; }
  __syncthreads();

  int row = blockIdx.x * 64 + tid;
  const float2* x2 = (const float2*)x;  // rows are 40B = 5 float2, 8B aligned
  float xv[INCH];
#pragma unroll
  for (int j = 0; j < 5; ++j) {
    float2 t = x2[row * 5 + j];
    xv[2 * j] = t.x;
    xv[2 * j + 1] = t.y;
  }

  float mu = 0.f;
#pragma unroll
  for (int i = 0; i < INCH; ++i) mu += xv[i];
  mu *= (1.0f / INCH);
  float var = 0.f;
#pragma unroll
  for (int i = 0; i < INCH; ++i) { float d = xv[i] - mu; var += d * d; }
  var *= (1.0f / INCH);
  float rstd = rsqrtf(var + 1e-5f);
  float h[INCH];
#pragma unroll
  for (int i = 0; i < INCH; ++i) h[i] = (xv[i] - mu) * rstd * sg[i] + sb[i];

  float acc[NQKV];
#pragma unroll
  for (int oc = 0; oc < NQKV; ++oc) {
    float s = 0.f;
#pragma unroll
    for (int i = 0; i < INCH; ++i) s += h[i] * sW[oc * INCH + i];
    acc[oc] = s;
  }

  // exp(s*scale) = exp2(s*scale*log2e): fold into q.
  const float QSC = 0.31622776601683794f * 1.4426950408889634f;

  unsigned short e[16];
  unsigned qw[8];
  // ---- Q row ----
#pragma unroll
  for (int i = 0; i < 16; ++i) e[i] = (i < OUTCH) ? f2bf(acc[i] * QSC) : 0;
#pragma unroll
  for (int i = 0; i < 8; ++i)
    qw[i] = (unsigned)e[2 * i] | ((unsigned)e[2 * i + 1] << 16);
  uint4* Qb = (uint4*)(ws + QB_OFF);
  Qb[row * 2 + 0] = make_uint4(qw[0], qw[1], qw[2], qw[3]);
  Qb[row * 2 + 1] = make_uint4(qw[4], qw[5], qw[6], qw[7]);
  // ---- K planes ----
#pragma unroll
  for (int i = 0; i < 16; ++i) e[i] = (i < OUTCH) ? f2bf(acc[OUTCH + i]) : 0;
#pragma unroll
  for (int i = 0; i < 8; ++i)
    qw[i] = (unsigned)e[2 * i] | ((unsigned)e[2 * i + 1] << 16);
  uint4* Kb = (uint4*)(ws + KB_OFF);
  Kb[row] = make_uint4(qw[0], qw[1], qw[2], qw[3]);          // plane 0
  Kb[NROWS + row] = make_uint4(qw[4], qw[5], qw[6], qw[7]);  // plane 1
  // ---- V^T scatter (2B stores into interleaved units) ----
  unsigned short* VTu = (unsigned short*)(ws + VT_OFF);
  int u0 = (row >> 3) * 16;
  int slot = row & 7;
#pragma unroll
  for (int d = 0; d < 16; ++d) {
    unsigned short v;
    if (d < OUTCH)       v = f2bf(acc[2 * OUTCH + d]);
    else if (d == OUTCH) v = 0x3F80;  // ones column -> softmax denominator
    else                 v = 0;
    VTu[(u0 + d) * 8 + slot] = v;
  }
}

// ---------------------------------------------------------------------------
// Kernel B (r9 structure + schedule tweaks only): full-K flash attention with
// in-block k-split. 256 blocks x 512 thr (8 waves). All waves share the
// block's 32 q-rows; wave w streams k-chunk [w*1024, +1024) through its
// PRIVATE double-buffered LDS region (no barriers in the main loop).
// Counted s_waitcnt vmcnt(8) keeps next-tile loads in flight (T4).
// Schedule tweaks this round: (1) no sched_barrier after the vmcnt asm --
// the "memory" clobber already orders global_load_lds vs ds_read, and the
// compiler is now free to hoist next-tile ds_reads into the exp shadow;
// (2) s_setprio(1) around the MFMA/exp core (T5, independent-wave attn);
// (3) qf preloaded before STAGE so its latency overlaps staging.
// Inner tile unchanged: S^T = mfma(K,Q); p = exp2(S); v_perm bf16 pack;
// permlane32_swap -> PV A-frags; O += mfma(P,V) x2; V ones-column gives l.
// No row-max (|s|<=~13, fp32-safe, softmax shift-invariant).
// ---------------------------------------------------------------------------
__global__ __launch_bounds__(512) void attn_kernel(const char* __restrict__ ws,
                                                   float* __restrict__ out) {
  __shared__ uint4 sStage[8 * 1024];        // 128 KB: per-wave [2][512] uint4
  __shared__ float sPart[8 * QBLK * 16];    // 16 KB: per-wave (o,l) tiles

  const int tid = threadIdx.x;
  const int lane = tid & 63;
  const int w = tid >> 6;       // wave id = k-chunk id
  const int h = lane >> 5;
  const int l31 = lane & 31;
  const int q0 = blockIdx.x * QBLK;
  const int kbase = w * KWAVE;

  const uint4* gK = (const uint4*)(ws + KB_OFF);  // [2][NROWS] 16B units
  const uint4* gV = (const uint4*)(ws + VT_OFF);  // [NROWS*2]  16B units

  uint4* myStage = sStage + w * 1024;  // 16 KB private: two 8KB buffers

  // Q fragment first: its global-load latency hides under the staging loads.
  short8 qf = *(const short8*)(ws + QB_OFF + (q0 + l31) * 32 + h * 16);

  // stage tile (128 k-rows) into buffer b: [0,256)=K planes, [256,512)=V^T
#define STAGE(b, k0)                                                         \
  {                                                                          \
    uint4* buf = myStage + (b) * 512;                                        \
    _Pragma("unroll") for (int c = 0; c < 2; ++c) {                          \
      _Pragma("unroll") for (int i = 0; i < 2; ++i) {                        \
        __builtin_amdgcn_global_load_lds(                                    \
            (const AS1 void*)(gK + c * NROWS + (k0) + i * 64 + lane),        \
            (AS3 void*)(buf + c * 128 + i * 64), 16, 0, 0);                  \
      }                                                                      \
    }                                                                        \
    _Pragma("unroll") for (int i = 0; i < 4; ++i) {                          \
      __builtin_amdgcn_global_load_lds(                                      \
          (const AS1 void*)(gV + (k0) * 2 + i * 64 + lane),                  \
          (AS3 void*)(buf + 256 + i * 64), 16, 0, 0);                        \
    }                                                                        \
  }

  STAGE(0, kbase)

  f32x16 oacc, zf;
#pragma unroll
  for (int r = 0; r < 16; ++r) { oacc[r] = 0.f; zf[r] = 0.f; }

  for (int t = 0; t < KWAVE / KTILE; ++t) {  // 8 tiles
    if (t < KWAVE / KTILE - 1) {
      STAGE((t + 1) & 1, kbase + (t + 1) * KTILE)
      asm volatile("s_waitcnt vmcnt(8)" ::: "memory");
    } else {
      asm volatile("s_waitcnt vmcnt(0)" ::: "memory");
    }

    const char* buf = (const char*)(myStage + (t & 1) * 512);
    const char* vb = buf + 4096;
    __builtin_amdgcn_s_setprio(1);
#pragma unroll
    for (int it = 0; it < KTILE / 32; ++it) {
      // K fragment: plane h, rows it*32 + l31 -> contiguous 16B/lane
      short8 kf = *(const short8*)(buf + h * 2048 + (it * 32 + l31) * 16);
      f32x16 s = __builtin_amdgcn_mfma_f32_32x32x16_bf16(kf, qf, zf, 0, 0, 0);

      float p[16];
#pragma unroll
      for (int r = 0; r < 16; ++r) p[r] = __builtin_amdgcn_exp2f(s[r]);

#define PK(a, b) __builtin_amdgcn_perm(__float_as_uint(b), __float_as_uint(a), 0x07060302u)
      unsigned P01 = PK(p[0], p[1]), P23 = PK(p[2], p[3]);
      unsigned P45 = PK(p[4], p[5]), P67 = PK(p[6], p[7]);
      unsigned P89 = PK(p[8], p[9]), Pab = PK(p[10], p[11]);
      unsigned Pcd = PK(p[12], p[13]), Pef = PK(p[14], p[15]);
#undef PK
      SWAP32(P01, P45);
      SWAP32(P23, P67);
      SWAP32(P89, Pcd);
      SWAP32(Pab, Pef);
      uvec4 c0 = {P01, P23, P45, P67};  // k 0..15: word j = P[q][k=8h+2j..]
      uvec4 c1 = {P89, Pab, Pcd, Pef};  // k 16..31
      short8 a0 = __builtin_bit_cast(short8, c0);
      short8 a1 = __builtin_bit_cast(short8, c1);

      // V fragments: lane holds V[k=16c'+8h+i][d=lane&15]
      short8 v0 = *(const short8*)(vb + (it * 4 + h) * 256 + (lane & 15) * 16);
      short8 v1 = *(const short8*)(vb + (it * 4 + 2 + h) * 256 + (lane & 15) * 16);

      oacc = __builtin_amdgcn_mfma_f32_32x32x16_bf16(a0, v0, oacc, 0, 0, 0);
      oacc = __builtin_amdgcn_mfma_f32_32x32x16_bf16(a1, v1, oacc, 0, 0, 0);
    }
    __builtin_amdgcn_s_setprio(0);
  }
#undef STAGE

  // wave-partials -> LDS; d = lane&31 < 12, q unique per (r,h)
  if (l31 < 12) {
#pragma unroll
    for (int r = 0; r < 16; ++r) {
      int q = (r & 3) + 8 * (r >> 2) + 4 * h;
      sPart[(w * QBLK + q) * 16 + l31] = oacc[r];
    }
  }
  __syncthreads();

  // in-block combine + normalize: thread (q = tid>>4, c = tid&15)
  {
    int q = tid >> 4;
    int c = tid & 15;
    if (c < OUTCH) {
      float o = 0.f, l = 0.f;
#pragma unroll
      for (int wv = 0; wv < 8; ++wv) {
        o += sPart[(wv * QBLK + q) * 16 + c];
        l += sPart[(wv * QBLK + q) * 16 + 11];
      }
      out[(size_t)(q0 + q) * OUTCH + c] = o / l;
    }
  }
}

extern "C" void kernel_launch(void* const* d_in, const int* in_sizes, int n_in,
                              void* d_out, int out_size, void* d_ws, size_t ws_size,
                              hipStream_t stream) {
  const float* x = (const float*)d_in[0];
  const float* gamma = (const float*)d_in[1];
  const float* beta = (const float*)d_in[2];
  const float* W = (const float*)d_in[3];
  char* ws = (char*)d_ws;  // 768 KB of Q/K/V planes
  float* out = (float*)d_out;

  qkv_ln_kernel<<<NROWS / 64, 64, 0, stream>>>(x, gamma, beta, W, ws);
  attn_kernel<<<NROWS / QBLK, 512, 0, stream>>>(ws, out);
}

// Round 13
// 21.783 us; speedup vs baseline: 1.0845x; 1.0292x over previous
//
#include <hip/hip_runtime.h>

#define NROWS 8192
#define INCH 10
#define NQKV 33
#define OUTCH 11
#define QBLK 32           // q-rows per block; all 8 waves share them
#define KWAVE 1024        // k-rows per wave (8 waves cover all 8192)
#define KTILE 128         // k-rows per staged V tile (double-buffered per wave)

typedef short short8 __attribute__((ext_vector_type(8)));
typedef float f32x16 __attribute__((ext_vector_type(16)));
typedef unsigned int uvec4 __attribute__((ext_vector_type(4)));

// ws byte layout:
//   QB_OFF: Q bf16 [NROWS][16ch] rows of 32B (scale*log2e folded into q)
//   KB_OFF: K bf16 planes [2][NROWS][16B]: plane c holds ch 8c..8c+7
//   VT_OFF: V^T bf16 interleaved: 16B unit u=(k>>3)*16+d holds V[(k&~7)+slot][d],
//           d=0..10 v, d=11 ones (softmax denom), d=12..15 zero
#define QB_OFF   0
#define KB_OFF   (NROWS * 32)
#define VT_OFF   (2 * NROWS * 32)

#define AS1 __attribute__((address_space(1)))
#define AS3 __attribute__((address_space(3)))

// v_permlane32_swap_b32 a, b:
//   a' = {a.lo32lanes, b.lo32lanes}, b' = {a.hi32lanes, b.hi32lanes}
#define SWAP32(a, b) asm("v_permlane32_swap_b32 %0, %1" : "+v"(a), "+v"(b))

__device__ inline unsigned short f2bf(float f) {
  unsigned u = __float_as_uint(f);
  unsigned r = (u + 0x7FFFu + ((u >> 16) & 1u)) >> 16;  // RNE
  return (unsigned short)r;
}

// ---------------------------------------------------------------------------
// Kernel A (r4-proven, unchanged): LayerNorm + Linear(10->33);
// emit bf16 Q rows, K planes, V^T.
// ---------------------------------------------------------------------------
__global__ __launch_bounds__(64) void qkv_ln_kernel(
    const float* __restrict__ x, const float* __restrict__ gamma,
    const float* __restrict__ beta, const float* __restrict__ W,
    char* __restrict__ ws) {
  __shared__ float sW[NQKV * INCH];
  __shared__ float sg[INCH];
  __shared__ float sb[INCH];
  int tid = threadIdx.x;
  for (int i = tid; i < NQKV * INCH; i += 64) sW[i] = W[i];
  if (tid < INCH) { sg[tid] = gamma[tid]; sb[tid] = beta[tid]; }
  __syncthreads();

  int row = blockIdx.x * 64 + tid;
  const float2* x2 = (const float2*)x;  // rows are 40B = 5 float2, 8B aligned
  float xv[INCH];
#pragma unroll
  for (int j = 0; j < 5; ++j) {
    float2 t = x2[row * 5 + j];
    xv[2 * j] = t.x;
    xv[2 * j + 1] = t.y;
  }

  float mu = 0.f;
#pragma unroll
  for (int i = 0; i < INCH; ++i) mu += xv[i];
  mu *= (1.0f / INCH);
  float var = 0.f;
#pragma unroll
  for (int i = 0; i < INCH; ++i) { float d = xv[i] - mu; var += d * d; }
  var *= (1.0f / INCH);
  float rstd = rsqrtf(var + 1e-5f);
  float h[INCH];
#pragma unroll
  for (int i = 0; i < INCH; ++i) h[i] = (xv[i] - mu) * rstd * sg[i] + sb[i];

  float acc[NQKV];
#pragma unroll
  for (int oc = 0; oc < NQKV; ++oc) {
    float s = 0.f;
#pragma unroll
    for (int i = 0; i < INCH; ++i) s += h[i] * sW[oc * INCH + i];
    acc[oc] = s;
  }

  // exp(s*scale) = exp2(s*scale*log2e): fold into q.
  const float QSC = 0.31622776601683794f * 1.4426950408889634f;

  unsigned short e[16];
  unsigned qw[8];
  // ---- Q row ----
#pragma unroll
  for (int i = 0; i < 16; ++i) e[i] = (i < OUTCH) ? f2bf(acc[i] * QSC) : 0;
#pragma unroll
  for (int i = 0; i < 8; ++i)
    qw[i] = (unsigned)e[2 * i] | ((unsigned)e[2 * i + 1] << 16);
  uint4* Qb = (uint4*)(ws + QB_OFF);
  Qb[row * 2 + 0] = make_uint4(qw[0], qw[1], qw[2], qw[3]);
  Qb[row * 2 + 1] = make_uint4(qw[4], qw[5], qw[6], qw[7]);
  // ---- K planes ----
#pragma unroll
  for (int i = 0; i < 16; ++i) e[i] = (i < OUTCH) ? f2bf(acc[OUTCH + i]) : 0;
#pragma unroll
  for (int i = 0; i < 8; ++i)
    qw[i] = (unsigned)e[2 * i] | ((unsigned)e[2 * i + 1] << 16);
  uint4* Kb = (uint4*)(ws + KB_OFF);
  Kb[row] = make_uint4(qw[0], qw[1], qw[2], qw[3]);          // plane 0
  Kb[NROWS + row] = make_uint4(qw[4], qw[5], qw[6], qw[7]);  // plane 1
  // ---- V^T scatter (2B stores into interleaved units) ----
  unsigned short* VTu = (unsigned short*)(ws + VT_OFF);
  int u0 = (row >> 3) * 16;
  int slot = row & 7;
#pragma unroll
  for (int d = 0; d < 16; ++d) {
    unsigned short v;
    if (d < OUTCH)       v = f2bf(acc[2 * OUTCH + d]);
    else if (d == OUTCH) v = 0x3F80;  // ones column -> softmax denominator
    else                 v = 0;
    VTu[(u0 + d) * 8 + slot] = v;
  }
}

// ---------------------------------------------------------------------------
// Kernel B (r12 + ONE change: K-fragments read direct from global, V-only
// LDS staging). K has no intra-wave reuse and its fragment read is already
// coalesced 16B/lane from L2-resident planes -> LDS round-trip was pure
// LDS-pipe cost (1 of 3 ds_reads + half the stage-writes). Per tile: issue
// 4 kf global loads, then STAGE(t+1)'s 4 V-loads, then vmcnt(4) -> kf and
// stage(t) complete, stage(t+1) stays in flight (in-order retirement).
// Inner tile otherwise unchanged: S^T = mfma(K,Q); p = exp2(S); v_perm
// bf16 pack; permlane32_swap -> PV A-frags; O += mfma(P,V) x2; V ones-
// column gives l. No row-max (|s|<=~13, fp32-safe, shift-invariant).
// Epilogue: one __syncthreads, sum 8 wave-partials from LDS, normalize.
// ---------------------------------------------------------------------------
__global__ __launch_bounds__(512) void attn_kernel(const char* __restrict__ ws,
                                                   float* __restrict__ out) {
  __shared__ uint4 sStage[8 * 512];         // 64 KB: per-wave [2][256] uint4 (V)
  __shared__ float sPart[8 * QBLK * 16];    // 16 KB: per-wave (o,l) tiles

  const int tid = threadIdx.x;
  const int lane = tid & 63;
  const int w = tid >> 6;       // wave id = k-chunk id
  const int h = lane >> 5;
  const int l31 = lane & 31;
  const int q0 = blockIdx.x * QBLK;
  const int kbase = w * KWAVE;

  const char* gK = ws + KB_OFF;                   // planes [2][NROWS][16B]
  const uint4* gV = (const uint4*)(ws + VT_OFF);  // [NROWS*2] 16B units

  uint4* myStage = sStage + w * 512;  // 8 KB private: two 4 KB V buffers

  // Q fragment first: its global-load latency hides under the staging loads.
  short8 qf = *(const short8*)(ws + QB_OFF + (q0 + l31) * 32 + h * 16);

  // stage V tile (128 k-rows = 256 units) into buffer b
#define STAGE(b, k0)                                                         \
  {                                                                          \
    uint4* buf = myStage + (b) * 256;                                        \
    _Pragma("unroll") for (int i = 0; i < 4; ++i) {                          \
      __builtin_amdgcn_global_load_lds(                                      \
          (const AS1 void*)(gV + (k0) * 2 + i * 64 + lane),                  \
          (AS3 void*)(buf + i * 64), 16, 0, 0);                              \
    }                                                                        \
  }

  STAGE(0, kbase)

  f32x16 oacc, zf;
#pragma unroll
  for (int r = 0; r < 16; ++r) { oacc[r] = 0.f; zf[r] = 0.f; }

  for (int t = 0; t < KWAVE / KTILE; ++t) {  // 8 tiles
    const int k0 = kbase + t * KTILE;
    // K fragments for this tile, direct from global (L2-hot, coalesced):
    // kf[it] = K[plane h][k0 + it*32 + l31], 16B/lane
    short8 kf0 = *(const short8*)(gK + (h * NROWS + k0 + 0 * 32 + l31) * 16);
    short8 kf1 = *(const short8*)(gK + (h * NROWS + k0 + 1 * 32 + l31) * 16);
    short8 kf2 = *(const short8*)(gK + (h * NROWS + k0 + 2 * 32 + l31) * 16);
    short8 kf3 = *(const short8*)(gK + (h * NROWS + k0 + 3 * 32 + l31) * 16);

    if (t < KWAVE / KTILE - 1) {
      STAGE((t + 1) & 1, k0 + KTILE)
      asm volatile("s_waitcnt vmcnt(4)" ::: "memory");
    } else {
      asm volatile("s_waitcnt vmcnt(0)" ::: "memory");
    }

    const char* vb = (const char*)(myStage + (t & 1) * 256);
    __builtin_amdgcn_s_setprio(1);
#pragma unroll
    for (int it = 0; it < KTILE / 32; ++it) {
      short8 kf = (it == 0) ? kf0 : (it == 1) ? kf1 : (it == 2) ? kf2 : kf3;
      f32x16 s = __builtin_amdgcn_mfma_f32_32x32x16_bf16(kf, qf, zf, 0, 0, 0);

      float p[16];
#pragma unroll
      for (int r = 0; r < 16; ++r) p[r] = __builtin_amdgcn_exp2f(s[r]);

#define PK(a, b) __builtin_amdgcn_perm(__float_as_uint(b), __float_as_uint(a), 0x07060302u)
      unsigned P01 = PK(p[0], p[1]), P23 = PK(p[2], p[3]);
      unsigned P45 = PK(p[4], p[5]), P67 = PK(p[6], p[7]);
      unsigned P89 = PK(p[8], p[9]), Pab = PK(p[10], p[11]);
      unsigned Pcd = PK(p[12], p[13]), Pef = PK(p[14], p[15]);
#undef PK
      SWAP32(P01, P45);
      SWAP32(P23, P67);
      SWAP32(P89, Pcd);
      SWAP32(Pab, Pef);
      uvec4 c0 = {P01, P23, P45, P67};  // k 0..15: word j = P[q][k=8h+2j..]
      uvec4 c1 = {P89, Pab, Pcd, Pef};  // k 16..31
      short8 a0 = __builtin_bit_cast(short8, c0);
      short8 a1 = __builtin_bit_cast(short8, c1);

      // V fragments from LDS: lane holds V[k=16c'+8h+i][d=lane&15]
      short8 v0 = *(const short8*)(vb + (it * 4 + h) * 256 + (lane & 15) * 16);
      short8 v1 = *(const short8*)(vb + (it * 4 + 2 + h) * 256 + (lane & 15) * 16);

      oacc = __builtin_amdgcn_mfma_f32_32x32x16_bf16(a0, v0, oacc, 0, 0, 0);
      oacc = __builtin_amdgcn_mfma_f32_32x32x16_bf16(a1, v1, oacc, 0, 0, 0);
    }
    __builtin_amdgcn_s_setprio(0);
  }
#undef STAGE

  // wave-partials -> LDS; d = lane&31 < 12, q unique per (r,h)
  if (l31 < 12) {
#pragma unroll
    for (int r = 0; r < 16; ++r) {
      int q = (r & 3) + 8 * (r >> 2) + 4 * h;
      sPart[(w * QBLK + q) * 16 + l31] = oacc[r];
    }
  }
  __syncthreads();

  // in-block combine + normalize: thread (q = tid>>4, c = tid&15)
  {
    int q = tid >> 4;
    int c = tid & 15;
    if (c < OUTCH) {
      float o = 0.f, l = 0.f;
#pragma unroll
      for (int wv = 0; wv < 8; ++wv) {
        o += sPart[(wv * QBLK + q) * 16 + c];
        l += sPart[(wv * QBLK + q) * 16 + 11];
      }
      out[(size_t)(q0 + q) * OUTCH + c] = o / l;
    }
  }
}

extern "C" void kernel_launch(void* const* d_in, const int* in_sizes, int n_in,
                              void* d_out, int out_size, void* d_ws, size_t ws_size,
                              hipStream_t stream) {
  const float* x = (const float*)d_in[0];
  const float* gamma = (const float*)d_in[1];
  const float* beta = (const float*)d_in[2];
  const float* W = (const float*)d_in[3];
  char* ws = (char*)d_ws;  // 768 KB of Q/K/V planes
  float* out = (float*)d_out;

  qkv_ln_kernel<<<NROWS / 64, 64, 0, stream>>>(x, gamma, beta, W, ws);
  attn_kernel<<<NROWS / QBLK, 512, 0, stream>>>(ws, out);
}

// Round 14
// 21.576 us; speedup vs baseline: 1.0949x; 1.0096x over previous
//
#include <hip/hip_runtime.h>

#define NROWS 8192
#define INCH 10
#define NQKV 33
#define OUTCH 11
#define QBLK 32           // q-rows per block; all 8 waves share them
#define KWAVE 1024        // k-rows per wave (8 waves cover all 8192)
#define KTILE 128         // k-rows per staged V tile (double-buffered per wave)

typedef short short8 __attribute__((ext_vector_type(8)));
typedef float f32x16 __attribute__((ext_vector_type(16)));
typedef unsigned int uvec4 __attribute__((ext_vector_type(4)));

// ws byte layout:
//   QB_OFF: Q bf16 [NROWS][16ch] rows of 32B (scale*log2e folded into q)
//   KB_OFF: K bf16 planes [2][NROWS][16B]: plane c holds ch 8c..8c+7
//   VT_OFF: V^T bf16 interleaved: 16B unit u=(k>>3)*16+d holds V[(k&~7)+slot][d],
//           d=0..10 v, d=11 ones (softmax denom), d=12..15 zero
#define QB_OFF   0
#define KB_OFF   (NROWS * 32)
#define VT_OFF   (2 * NROWS * 32)

#define AS1 __attribute__((address_space(1)))
#define AS3 __attribute__((address_space(3)))

// v_permlane32_swap_b32 a, b:
//   a' = {a.lo32lanes, b.lo32lanes}, b' = {a.hi32lanes, b.hi32lanes}
#define SWAP32(a, b) asm("v_permlane32_swap_b32 %0, %1" : "+v"(a), "+v"(b))

__device__ inline unsigned short f2bf(float f) {
  unsigned u = __float_as_uint(f);
  unsigned r = (u + 0x7FFFu + ((u >> 16) & 1u)) >> 16;  // RNE
  return (unsigned short)r;
}

// ---------------------------------------------------------------------------
// Kernel A (r4-proven, unchanged): LayerNorm + Linear(10->33);
// emit bf16 Q rows, K planes, V^T.
// ---------------------------------------------------------------------------
__global__ __launch_bounds__(64) void qkv_ln_kernel(
    const float* __restrict__ x, const float* __restrict__ gamma,
    const float* __restrict__ beta, const float* __restrict__ W,
    char* __restrict__ ws) {
  __shared__ float sW[NQKV * INCH];
  __shared__ float sg[INCH];
  __shared__ float sb[INCH];
  int tid = threadIdx.x;
  for (int i = tid; i < NQKV * INCH; i += 64) sW[i] = W[i];
  if (tid < INCH) { sg[tid] = gamma[tid]; sb[tid] = beta[tid]; }
  __syncthreads();

  int row = blockIdx.x * 64 + tid;
  const float2* x2 = (const float2*)x;  // rows are 40B = 5 float2, 8B aligned
  float xv[INCH];
#pragma unroll
  for (int j = 0; j < 5; ++j) {
    float2 t = x2[row * 5 + j];
    xv[2 * j] = t.x;
    xv[2 * j + 1] = t.y;
  }

  float mu = 0.f;
#pragma unroll
  for (int i = 0; i < INCH; ++i) mu += xv[i];
  mu *= (1.0f / INCH);
  float var = 0.f;
#pragma unroll
  for (int i = 0; i < INCH; ++i) { float d = xv[i] - mu; var += d * d; }
  var *= (1.0f / INCH);
  float rstd = rsqrtf(var + 1e-5f);
  float h[INCH];
#pragma unroll
  for (int i = 0; i < INCH; ++i) h[i] = (xv[i] - mu) * rstd * sg[i] + sb[i];

  float acc[NQKV];
#pragma unroll
  for (int oc = 0; oc < NQKV; ++oc) {
    float s = 0.f;
#pragma unroll
    for (int i = 0; i < INCH; ++i) s += h[i] * sW[oc * INCH + i];
    acc[oc] = s;
  }

  // exp(s*scale) = exp2(s*scale*log2e): fold into q.
  const float QSC = 0.31622776601683794f * 1.4426950408889634f;

  unsigned short e[16];
  unsigned qw[8];
  // ---- Q row ----
#pragma unroll
  for (int i = 0; i < 16; ++i) e[i] = (i < OUTCH) ? f2bf(acc[i] * QSC) : 0;
#pragma unroll
  for (int i = 0; i < 8; ++i)
    qw[i] = (unsigned)e[2 * i] | ((unsigned)e[2 * i + 1] << 16);
  uint4* Qb = (uint4*)(ws + QB_OFF);
  Qb[row * 2 + 0] = make_uint4(qw[0], qw[1], qw[2], qw[3]);
  Qb[row * 2 + 1] = make_uint4(qw[4], qw[5], qw[6], qw[7]);
  // ---- K planes ----
#pragma unroll
  for (int i = 0; i < 16; ++i) e[i] = (i < OUTCH) ? f2bf(acc[OUTCH + i]) : 0;
#pragma unroll
  for (int i = 0; i < 8; ++i)
    qw[i] = (unsigned)e[2 * i] | ((unsigned)e[2 * i + 1] << 16);
  uint4* Kb = (uint4*)(ws + KB_OFF);
  Kb[row] = make_uint4(qw[0], qw[1], qw[2], qw[3]);          // plane 0
  Kb[NROWS + row] = make_uint4(qw[4], qw[5], qw[6], qw[7]);  // plane 1
  // ---- V^T scatter (2B stores into interleaved units) ----
  unsigned short* VTu = (unsigned short*)(ws + VT_OFF);
  int u0 = (row >> 3) * 16;
  int slot = row & 7;
#pragma unroll
  for (int d = 0; d < 16; ++d) {
    unsigned short v;
    if (d < OUTCH)       v = f2bf(acc[2 * OUTCH + d]);
    else if (d == OUTCH) v = 0x3F80;  // ones column -> softmax denominator
    else                 v = 0;
    VTu[(u0 + d) * 8 + slot] = v;
  }
}

// ---------------------------------------------------------------------------
// Kernel B (r13 + ONE change: K-fragments register-PREFETCHED one tile
// ahead, double-buffered in VGPRs like V is in LDS). r13 issued tile t's
// kf loads right before the vmcnt that required them complete -> ~200-cyc
// exposed L2 latency per tile. Now at tile t we issue STAGE(t+1) +
// LOADK(t+1) and wait vmcnt(8): the 8 oldest (stage(t)+kf(t)) retire, the
// 8 newest (stage(t+1)+kf(t+1)) stay in flight (FIFO retirement).
// Inner tile unchanged: S^T = mfma(K,Q); p = exp2(S); v_perm bf16 pack;
// permlane32_swap -> PV A-frags; O += mfma(P,V) x2; V ones-column gives l.
// No row-max (|s|<=~13, fp32-safe, softmax shift-invariant).
// Epilogue: one __syncthreads, sum 8 wave-partials from LDS, normalize.
// ---------------------------------------------------------------------------
__global__ __launch_bounds__(512) void attn_kernel(const char* __restrict__ ws,
                                                   float* __restrict__ out) {
  __shared__ uint4 sStage[8 * 512];         // 64 KB: per-wave [2][256] uint4 (V)
  __shared__ float sPart[8 * QBLK * 16];    // 16 KB: per-wave (o,l) tiles

  const int tid = threadIdx.x;
  const int lane = tid & 63;
  const int w = tid >> 6;       // wave id = k-chunk id
  const int h = lane >> 5;
  const int l31 = lane & 31;
  const int q0 = blockIdx.x * QBLK;
  const int kbase = w * KWAVE;

  const char* gK = ws + KB_OFF;                   // planes [2][NROWS][16B]
  const uint4* gV = (const uint4*)(ws + VT_OFF);  // [NROWS*2] 16B units

  uint4* myStage = sStage + w * 512;  // 8 KB private: two 4 KB V buffers

  // Q fragment first: its global-load latency hides under the staging loads.
  short8 qf = *(const short8*)(ws + QB_OFF + (q0 + l31) * 32 + h * 16);

  // stage V tile (128 k-rows = 256 units) into buffer b
#define STAGE(b, k0)                                                         \
  {                                                                          \
    uint4* buf = myStage + (b) * 256;                                        \
    _Pragma("unroll") for (int i = 0; i < 4; ++i) {                          \
      __builtin_amdgcn_global_load_lds(                                      \
          (const AS1 void*)(gV + (k0) * 2 + i * 64 + lane),                  \
          (AS3 void*)(buf + i * 64), 16, 0, 0);                              \
    }                                                                        \
  }

  // K fragments for one tile, direct from global (coalesced 16B/lane)
#define LOADK(d0, d1, d2, d3, k0)                                            \
  d0 = *(const short8*)(gK + (h * NROWS + (k0) + 0 + l31) * 16);             \
  d1 = *(const short8*)(gK + (h * NROWS + (k0) + 32 + l31) * 16);            \
  d2 = *(const short8*)(gK + (h * NROWS + (k0) + 64 + l31) * 16);            \
  d3 = *(const short8*)(gK + (h * NROWS + (k0) + 96 + l31) * 16);

  f32x16 oacc, zf;
#pragma unroll
  for (int r = 0; r < 16; ++r) { oacc[r] = 0.f; zf[r] = 0.f; }

  // one 128-row tile's compute (4 x 32-k subtiles)
  auto tileCompute = [&](const char* vb, short8 f0, short8 f1, short8 f2,
                         short8 f3) {
    __builtin_amdgcn_s_setprio(1);
#pragma unroll
    for (int it = 0; it < KTILE / 32; ++it) {
      short8 kf = (it == 0) ? f0 : (it == 1) ? f1 : (it == 2) ? f2 : f3;
      f32x16 s = __builtin_amdgcn_mfma_f32_32x32x16_bf16(kf, qf, zf, 0, 0, 0);

      float p[16];
#pragma unroll
      for (int r = 0; r < 16; ++r) p[r] = __builtin_amdgcn_exp2f(s[r]);

#define PK(a, b) __builtin_amdgcn_perm(__float_as_uint(b), __float_as_uint(a), 0x07060302u)
      unsigned P01 = PK(p[0], p[1]), P23 = PK(p[2], p[3]);
      unsigned P45 = PK(p[4], p[5]), P67 = PK(p[6], p[7]);
      unsigned P89 = PK(p[8], p[9]), Pab = PK(p[10], p[11]);
      unsigned Pcd = PK(p[12], p[13]), Pef = PK(p[14], p[15]);
#undef PK
      SWAP32(P01, P45);
      SWAP32(P23, P67);
      SWAP32(P89, Pcd);
      SWAP32(Pab, Pef);
      uvec4 c0 = {P01, P23, P45, P67};  // k 0..15: word j = P[q][k=8h+2j..]
      uvec4 c1 = {P89, Pab, Pcd, Pef};  // k 16..31
      short8 a0 = __builtin_bit_cast(short8, c0);
      short8 a1 = __builtin_bit_cast(short8, c1);

      // V fragments from LDS: lane holds V[k=16c'+8h+i][d=lane&15]
      short8 v0 = *(const short8*)(vb + (it * 4 + h) * 256 + (lane & 15) * 16);
      short8 v1 = *(const short8*)(vb + (it * 4 + 2 + h) * 256 + (lane & 15) * 16);

      oacc = __builtin_amdgcn_mfma_f32_32x32x16_bf16(a0, v0, oacc, 0, 0, 0);
      oacc = __builtin_amdgcn_mfma_f32_32x32x16_bf16(a1, v1, oacc, 0, 0, 0);
    }
    __builtin_amdgcn_s_setprio(0);
  };

  short8 ka0, ka1, ka2, ka3, kb0, kb1, kb2, kb3;

  // prologue: V tile 0 -> LDS, K tile 0 -> regs (8 loads in flight)
  STAGE(0, kbase)
  LOADK(ka0, ka1, ka2, ka3, kbase)

  for (int t = 0; t < KWAVE / KTILE; t += 2) {  // 8 tiles, 2 per iteration
    // ---- even tile t (in ka): prefetch tile t+1 into kb + LDS buf 1 ----
    {
      const int k0 = kbase + t * KTILE;
      STAGE(1, k0 + KTILE)
      LOADK(kb0, kb1, kb2, kb3, k0 + KTILE)
      asm volatile("s_waitcnt vmcnt(8)" ::: "memory");
      tileCompute((const char*)myStage, ka0, ka1, ka2, ka3);
    }
    // ---- odd tile t+1 (in kb): prefetch tile t+2 into ka + LDS buf 0 ----
    {
      const int k0 = kbase + (t + 1) * KTILE;
      if (t + 2 < KWAVE / KTILE) {
        STAGE(0, k0 + KTILE)
        LOADK(ka0, ka1, ka2, ka3, k0 + KTILE)
        asm volatile("s_waitcnt vmcnt(8)" ::: "memory");
      } else {
        asm volatile("s_waitcnt vmcnt(0)" ::: "memory");
      }
      tileCompute((const char*)(myStage + 256), kb0, kb1, kb2, kb3);
    }
  }
#undef STAGE
#undef LOADK

  // wave-partials -> LDS; d = lane&31 < 12, q unique per (r,h)
  if (l31 < 12) {
#pragma unroll
    for (int r = 0; r < 16; ++r) {
      int q = (r & 3) + 8 * (r >> 2) + 4 * h;
      sPart[(w * QBLK + q) * 16 + l31] = oacc[r];
    }
  }
  __syncthreads();

  // in-block combine + normalize: thread (q = tid>>4, c = tid&15)
  {
    int q = tid >> 4;
    int c = tid & 15;
    if (c < OUTCH) {
      float o = 0.f, l = 0.f;
#pragma unroll
      for (int wv = 0; wv < 8; ++wv) {
        o += sPart[(wv * QBLK + q) * 16 + c];
        l += sPart[(wv * QBLK + q) * 16 + 11];
      }
      out[(size_t)(q0 + q) * OUTCH + c] = o / l;
    }
  }
}

extern "C" void kernel_launch(void* const* d_in, const int* in_sizes, int n_in,
                              void* d_out, int out_size, void* d_ws, size_t ws_size,
                              hipStream_t stream) {
  const float* x = (const float*)d_in[0];
  const float* gamma = (const float*)d_in[1];
  const float* beta = (const float*)d_in[2];
  const float* W = (const float*)d_in[3];
  char* ws = (char*)d_ws;  // 768 KB of Q/K/V planes
  float* out = (float*)d_out;

  qkv_ln_kernel<<<NROWS / 64, 64, 0, stream>>>(x, gamma, beta, W, ws);
  attn_kernel<<<NROWS / QBLK, 512, 0, stream>>>(ws, out);
}